// Round 5
// baseline (46182.016 us; speedup 1.0000x reference)
//
#include <hip/hip_runtime.h>
#include <stdint.h>

#define T_SEQ 2048
#define NB 32
#define NH 1024
#define HH (NH*NH)
#define HIST_ELEMS ((size_t)T_SEQ*NB*NH)
#define TEAM 32
#define SLOT (NB*NH*4)          // one parity slot of tagged state: 128 KiB

typedef __attribute__((ext_vector_type(8))) short bf16x8;
typedef __attribute__((ext_vector_type(4))) float f32x4;
typedef __attribute__((ext_vector_type(4))) int   i32x4;
typedef __attribute__((ext_vector_type(4))) short s16x4;

__device__ __forceinline__ unsigned short bf16rne(float f){
  union { float f; unsigned u; } v; v.f = f;
  unsigned u = v.u;
  return (unsigned short)((u + 0x7FFFu + ((u >> 16) & 1u)) >> 16);
}
__device__ __forceinline__ float bf16tof(unsigned short s){
  union { unsigned u; float f; } v; v.u = ((unsigned)s) << 16; return v.f;
}
__device__ __forceinline__ float fast_tanh(float x){
  float ax = fabsf(x);
  float e  = __expf(-2.0f*ax);
  float t  = (1.0f - e) / (1.0f + e);
  return copysignf(t, x);
}

// agent-scope (device-coherent, compiler-tracked) tagged-state accessors
__device__ __forceinline__ uint64_t ld_state(const uint64_t* p){
  return __hip_atomic_load(p, __ATOMIC_RELAXED, __HIP_MEMORY_SCOPE_AGENT);
}
__device__ __forceinline__ void st_state(uint64_t* p, uint64_t v){
  __hip_atomic_store(p, v, __ATOMIC_RELAXED, __HIP_MEMORY_SCOPE_AGENT);
}

// one u64 = two tagged words {col j (lo), col j+1 (hi)}; word = val16<<16 | tag16
__device__ __forceinline__ unsigned frag_word(uint64_t w, unsigned rep, unsigned &bad){
  unsigned lo = (unsigned)w, hi = (unsigned)(w >> 32);
  bad |= (((lo & 0xFFFFu) | (hi << 16)) ^ rep);
  return (lo >> 16) | (hi & 0xFFFF0000u);
}

// =====================================================================
// Kernel 1: pre0 = x @ Wih0^T + b_ih0 + b_hh0   (unchanged — validated)
// =====================================================================
__global__ __launch_bounds__(256)
void pre_gemm(const float* __restrict__ x,
              const float* __restrict__ Wih,
              const float* __restrict__ bih,
              const float* __restrict__ bhh,
              _Float16* __restrict__ pre0)
{
  __shared__ float As[128][36];
  const int tid  = threadIdx.x;
  const int lane = tid & 63;
  const int wave = tid >> 6;
  const int l15  = lane & 15;
  const int l4   = lane >> 4;
  const int n0   = blockIdx.x * 128;
  const int m0   = blockIdx.y * 128;
  const int qm   = wave >> 1;
  const int qn   = wave & 1;

  f32x4 acc[4][4];
  #pragma unroll
  for (int i = 0; i < 4; ++i)
    #pragma unroll
    for (int j = 0; j < 4; ++j) acc[i][j] = (f32x4){0.f,0.f,0.f,0.f};

  const int sr = tid >> 1;
  const int sh = tid & 1;
  const float* xrow = x + (size_t)(m0 + sr)*NH + sh*16;

  for (int kb = 0; kb < 32; ++kb){
    __syncthreads();
    {
      const float* src = xrow + kb*32;
      f32x4 v0 = *(const f32x4*)(src + 0);
      f32x4 v1 = *(const f32x4*)(src + 4);
      f32x4 v2 = *(const f32x4*)(src + 8);
      f32x4 v3 = *(const f32x4*)(src + 12);
      float* dst = &As[sr][sh*16];
      *(f32x4*)(dst + 0)  = v0;
      *(f32x4*)(dst + 4)  = v1;
      *(f32x4*)(dst + 8)  = v2;
      *(f32x4*)(dst + 12) = v3;
    }
    __syncthreads();

    bf16x8 ahi[4], alo[4];
    #pragma unroll
    for (int mt = 0; mt < 4; ++mt){
      const float* ap = &As[64*qm + 16*mt + l15][l4*8];
      #pragma unroll
      for (int j = 0; j < 8; ++j){
        float a = ap[j];
        unsigned short hb = bf16rne(a);
        ahi[mt][j] = (short)hb;
        alo[mt][j] = (short)bf16rne(a - bf16tof(hb));
      }
    }
    #pragma unroll
    for (int nf = 0; nf < 4; ++nf){
      const int c = n0 + 64*qn + 16*nf + l15;
      const float* wp = Wih + (size_t)c*NH + kb*32 + l4*8;
      bf16x8 bf;
      #pragma unroll
      for (int j = 0; j < 8; ++j) bf[j] = (short)bf16rne(wp[j]);
      #pragma unroll
      for (int mt = 0; mt < 4; ++mt){
        acc[mt][nf] = __builtin_amdgcn_mfma_f32_16x16x32_bf16(ahi[mt], bf, acc[mt][nf], 0,0,0);
        acc[mt][nf] = __builtin_amdgcn_mfma_f32_16x16x32_bf16(alo[mt], bf, acc[mt][nf], 0,0,0);
      }
    }
  }

  #pragma unroll
  for (int nf = 0; nf < 4; ++nf){
    const int c = n0 + 64*qn + 16*nf + l15;
    const float bv = bih[c] + bhh[c];
    #pragma unroll
    for (int mt = 0; mt < 4; ++mt){
      const int mb = m0 + 64*qm + 16*mt + l4*4;
      #pragma unroll
      for (int j = 0; j < 4; ++j)
        pre0[(size_t)(mb + j)*NH + c] = (_Float16)(acc[mt][nf][j] + bv);
    }
  }
}

// =====================================================================
// Kernel 2: 32-WG persistent recurrence, self-validating tagged state.
// Tag = phase+2 (memset-0 each launch = invalid; 0xAAAA poison invalid).
// All state traffic via agent-scope HIP atomics (compiler-tracked: no
// inline-asm loads, no waitcnt hazards, spill-safe). No flags/fences.
// =====================================================================
__global__ __launch_bounds__(256, 1)
void rnn_seq(const float* __restrict__ h0in,
             const float* __restrict__ Wih,
             const float* __restrict__ Whh,
             const float* __restrict__ bih,
             const float* __restrict__ bhh,
             const _Float16* __restrict__ pre0,
             float* __restrict__ dout,
             char* __restrict__ ws)
{
  const int tid  = threadIdx.x;
  const int lane = tid & 63;
  const int wave = tid >> 6;
  const int l15  = lane & 15;
  const int l4   = lane >> 4;
  const int rank = blockIdx.x;     // 0..31
  const int c0   = rank * 32;

  char* H0 = ws + 4096;            // [2][32][1024] tagged u32 (memset 0/launch)
  char* H1 = ws + 4096 + 2*SLOT;

  // ---- static weight A-fragments: [0]=Whh0 [1]=Wih1 [2]=Whh1 (proven R3) ----
  bf16x8 wA[3][2][8];
  #pragma unroll
  for (int cf = 0; cf < 2; ++cf){
    const size_t row = (size_t)(c0 + cf*16 + l15) * NH;
    const float* s0 = Whh + row;
    const float* s1 = Wih + HH + row;
    const float* s2 = Whh + HH + row;
    #pragma unroll
    for (int s = 0; s < 8; ++s){
      const int k = wave*256 + s*32 + l4*8;
      #pragma unroll
      for (int j = 0; j < 8; ++j){
        wA[0][cf][s][j] = (short)bf16rne(s0[k+j]);
        wA[1][cf][s][j] = (short)bf16rne(s1[k+j]);
        wA[2][cf][s][j] = (short)bf16rne(s2[k+j]);
      }
    }
  }

  // ---- epilogue mapping: thread -> (batch, 4-col block), both layers ----
  const int eb   = tid >> 3;
  const int ecb  = tid & 7;
  const int ecol = c0 + ecb*4;

  f32x4 bias1;
  #pragma unroll
  for (int j = 0; j < 4; ++j)
    bias1[j] = bih[NH + ecol + j] + bhh[NH + ecol + j];

  // ---- initial state h(-1): tag = 1, parity-1 slots ----
  {
    const float* hs0 = h0in + (size_t)eb*NH + ecol;
    const float* hs1 = h0in + (size_t)NB*NH + (size_t)eb*NH + ecol;
    #pragma unroll
    for (int half = 0; half < 2; ++half){
      unsigned a0 = (((unsigned)bf16rne(hs0[2*half]))   << 16) | 1u;
      unsigned a1 = (((unsigned)bf16rne(hs0[2*half+1])) << 16) | 1u;
      unsigned b0 = (((unsigned)bf16rne(hs1[2*half]))   << 16) | 1u;
      unsigned b1 = (((unsigned)bf16rne(hs1[2*half+1])) << 16) | 1u;
      st_state((uint64_t*)(H0 + SLOT + (size_t)(eb*NH + ecol + 2*half)*4),
               (uint64_t)a0 | ((uint64_t)a1 << 32));
      st_state((uint64_t*)(H1 + SLOT + (size_t)(eb*NH + ecol + 2*half)*4),
               (uint64_t)b0 | ((uint64_t)b1 << 32));
    }
  }

  __shared__ float scr[4][8][16][20];   // padded (proven R3)
  long budget = 1L << 17;               // bounded retries: degrade, never hang

  for (int p = 0; p <= T_SEQ; ++p){
    const bool doL0 = (p < T_SEQ);
    const bool doL1 = (p >= 1);

    // prefetch pre0 slice (plain cached load; consumed in epilogue)
    s16x4 praw = {0,0,0,0};
    if (doL0)
      praw = *(const s16x4*)(pre0 + (size_t)p*(NB*NH) + (size_t)eb*NH + ecol);

    // ---- self-validating gather: h0(p-1) tag p+1; h1(p-2) tag p ----
    const unsigned rep0 = (unsigned)(p + 1) * 0x10001u;
    const unsigned rep1 = (unsigned)p       * 0x10001u;
    const char* h0rd = H0 + (size_t)((p-1)&1)*SLOT;
    const char* h1rd = H1 + (size_t)((p-2)&1)*SLOT;

    i32x4 f0[2][8], f1[2][8];
    bool need0 = true, need1 = doL1;
    int round = 0;
    while (need0 || need1){
      if (need0){
        unsigned bad = 0;
        #pragma unroll
        for (int bt = 0; bt < 2; ++bt){
          const uint64_t* rb =
            (const uint64_t*)(h0rd + (size_t)(bt*16 + l15)*4096 + wave*1024 + l4*32);
          #pragma unroll
          for (int s = 0; s < 8; ++s){
            uint64_t w0 = ld_state(rb + s*16 + 0);
            uint64_t w1 = ld_state(rb + s*16 + 1);
            uint64_t w2 = ld_state(rb + s*16 + 2);
            uint64_t w3 = ld_state(rb + s*16 + 3);
            i32x4 f;
            f[0] = (int)frag_word(w0, rep0, bad);
            f[1] = (int)frag_word(w1, rep0, bad);
            f[2] = (int)frag_word(w2, rep0, bad);
            f[3] = (int)frag_word(w3, rep0, bad);
            f0[bt][s] = f;
          }
        }
        if (__all((int)(bad == 0))) need0 = false;
      }
      if (need1){
        unsigned bad = 0;
        #pragma unroll
        for (int bt = 0; bt < 2; ++bt){
          const uint64_t* rb =
            (const uint64_t*)(h1rd + (size_t)(bt*16 + l15)*4096 + wave*1024 + l4*32);
          #pragma unroll
          for (int s = 0; s < 8; ++s){
            uint64_t w0 = ld_state(rb + s*16 + 0);
            uint64_t w1 = ld_state(rb + s*16 + 1);
            uint64_t w2 = ld_state(rb + s*16 + 2);
            uint64_t w3 = ld_state(rb + s*16 + 3);
            i32x4 f;
            f[0] = (int)frag_word(w0, rep1, bad);
            f[1] = (int)frag_word(w1, rep1, bad);
            f[2] = (int)frag_word(w2, rep1, bad);
            f[3] = (int)frag_word(w3, rep1, bad);
            f1[bt][s] = f;
          }
        }
        if (__all((int)(bad == 0))) need1 = false;
      }
      if (need0 || need1){
        if (--budget < 0) break;
        if (++round > 2) __builtin_amdgcn_s_sleep(1);
      }
    }

    // ---- MFMA partial sums over this wave's K-slice (proven R3 mapping) ----
    f32x4 acc0[2][2] = {{{0,0,0,0},{0,0,0,0}},{{0,0,0,0},{0,0,0,0}}};
    f32x4 acc1[2][2] = {{{0,0,0,0},{0,0,0,0}},{{0,0,0,0},{0,0,0,0}}};
    #pragma unroll
    for (int cf = 0; cf < 2; ++cf){
      #pragma unroll
      for (int bt = 0; bt < 2; ++bt){
        #pragma unroll
        for (int s = 0; s < 8; ++s){
          bf16x8 b0 = __builtin_bit_cast(bf16x8, f0[bt][s]);
          if (doL0)
            acc0[cf][bt] = __builtin_amdgcn_mfma_f32_16x16x32_bf16(wA[0][cf][s], b0, acc0[cf][bt], 0,0,0);
          if (doL1){
            acc1[cf][bt] = __builtin_amdgcn_mfma_f32_16x16x32_bf16(wA[1][cf][s], b0, acc1[cf][bt], 0,0,0);
            bf16x8 b1 = __builtin_bit_cast(bf16x8, f1[bt][s]);
            acc1[cf][bt] = __builtin_amdgcn_mfma_f32_16x16x32_bf16(wA[2][cf][s], b1, acc1[cf][bt], 0,0,0);
          }
        }
      }
    }

    // ---- cross-wave K reduction via LDS ----
    __syncthreads();   // WAR vs previous phase's reduce reads
    #pragma unroll
    for (int cf = 0; cf < 2; ++cf){
      #pragma unroll
      for (int bt = 0; bt < 2; ++bt){
        *(f32x4*)&scr[wave][(cf<<1)|bt][l15][l4*4]   = acc0[cf][bt];
        *(f32x4*)&scr[wave][4|(cf<<1)|bt][l15][l4*4] = acc1[cf][bt];
      }
    }
    __syncthreads();

    const int fL0 = ((ecb >> 2) << 1) | (eb >> 4);
    f32x4 s0v = {0,0,0,0}, s1v = {0,0,0,0};
    #pragma unroll
    for (int w = 0; w < 4; ++w){
      s0v += *(const f32x4*)&scr[w][fL0][eb & 15][(ecb & 3)*4];
      s1v += *(const f32x4*)&scr[w][4|fL0][eb & 15][(ecb & 3)*4];
    }

    // ---- activations; tagged state stores (agent-scope atomics) ----
    const unsigned wtag0 = (unsigned)(p + 2);   // tagof(p)
    const unsigned wtag1 = (unsigned)(p + 1);   // tagof(p-1)
    float hv0[4], hv1[4];
    if (doL0){
      union { s16x4 v; _Float16 h[4]; } pu; pu.v = praw;
      #pragma unroll
      for (int j = 0; j < 4; ++j)
        hv0[j] = fast_tanh(s0v[j] + (float)pu.h[j]);
      char* wb = H0 + (size_t)(p&1)*SLOT + (size_t)(eb*NH + ecol)*4;
      #pragma unroll
      for (int half = 0; half < 2; ++half){
        unsigned a0 = (((unsigned)bf16rne(hv0[2*half]))   << 16) | wtag0;
        unsigned a1 = (((unsigned)bf16rne(hv0[2*half+1])) << 16) | wtag0;
        st_state((uint64_t*)(wb + 8*half), (uint64_t)a0 | ((uint64_t)a1 << 32));
      }
    }
    if (doL1){
      #pragma unroll
      for (int j = 0; j < 4; ++j)
        hv1[j] = fast_tanh(s1v[j] + bias1[j]);
      char* wb = H1 + (size_t)((p-1)&1)*SLOT + (size_t)(eb*NH + ecol)*4;
      #pragma unroll
      for (int half = 0; half < 2; ++half){
        unsigned a0 = (((unsigned)bf16rne(hv1[2*half]))   << 16) | wtag1;
        unsigned a1 = (((unsigned)bf16rne(hv1[2*half+1])) << 16) | wtag1;
        st_state((uint64_t*)(wb + 8*half), (uint64_t)a0 | ((uint64_t)a1 << 32));
      }
    }

    // ---- HBM outputs (plain stores, off the critical chain) ----
    if (doL1){
      f32x4 o = {hv1[0], hv1[1], hv1[2], hv1[3]};
      *(f32x4*)(dout + (size_t)(p-1)*(NB*NH) + (size_t)eb*NH + ecol) = o;
      if (p == T_SEQ)
        *(f32x4*)(dout + HIST_ELEMS + (size_t)NB*NH + (size_t)eb*NH + ecol) = o;
    }
    if (doL0 && p == T_SEQ-1){
      f32x4 o = {hv0[0], hv0[1], hv0[2], hv0[3]};
      *(f32x4*)(dout + HIST_ELEMS + (size_t)eb*NH + ecol) = o;
    }
  }
}

extern "C" void kernel_launch(void* const* d_in, const int* in_sizes, int n_in,
                              void* d_out, int out_size, void* d_ws, size_t ws_size,
                              hipStream_t stream)
{
  (void)in_sizes; (void)n_in; (void)out_size;
  const float* x   = (const float*)d_in[0];
  const float* h0  = (const float*)d_in[1];
  const float* Wih = (const float*)d_in[2];
  const float* Whh = (const float*)d_in[3];
  const float* bih = (const float*)d_in[4];
  const float* bhh = (const float*)d_in[5];
  float* out = (float*)d_out;
  char*  ws  = (char*)d_ws;

  const size_t PRE0_OFF = (size_t)1 << 20;
  const size_t NEED = PRE0_OFF + (size_t)T_SEQ*NB*NH*sizeof(_Float16);
  if (ws_size < NEED) return;

  _Float16* pre0 = (_Float16*)(ws + PRE0_OFF);

  // zero ALL tagged-state slots each launch: tag 0 = invalid
  hipMemsetAsync(ws, 0, 4096 + 4*(size_t)SLOT, stream);
  pre_gemm<<<dim3(8, 512), 256, 0, stream>>>(x, Wih, bih, bhh, pre0);
  rnn_seq<<<dim3(TEAM), 256, 0, stream>>>(h0, Wih, Whh, bih, bhh, pre0, out, ws);
}

// Round 6
// 15745.532 us; speedup vs baseline: 2.9330x; 2.9330x over previous
//
#include <hip/hip_runtime.h>
#include <stdint.h>

#define T_SEQ 2048
#define NB 32
#define NH 1024
#define HH (NH*NH)
#define HIST_ELEMS ((size_t)T_SEQ*NB*NH)
#define TEAM 32

typedef __attribute__((ext_vector_type(8))) short bf16x8;
typedef __attribute__((ext_vector_type(4))) float f32x4;
typedef __attribute__((ext_vector_type(4))) int   i32x4;
typedef __attribute__((ext_vector_type(2))) int   i32x2;
typedef __attribute__((ext_vector_type(4))) short s16x4;

__device__ __forceinline__ unsigned short bf16rne(float f){
  union { float f; unsigned u; } v; v.f = f;
  unsigned u = v.u;
  return (unsigned short)((u + 0x7FFFu + ((u >> 16) & 1u)) >> 16);
}
__device__ __forceinline__ float bf16tof(unsigned short s){
  union { unsigned u; float f; } v; v.u = ((unsigned)s) << 16; return v.f;
}
__device__ __forceinline__ float fast_tanh(float x){
  float ax = fabsf(x);
  float e  = __expf(-2.0f*ax);
  float t  = (1.0f - e) / (1.0f + e);
  return copysignf(t, x);
}

// ---- device-scope coherent ops (sc0 sc1 — proven R1/R3) ----
__device__ __forceinline__ i32x4 ld128_c(const void* p){
  i32x4 d;
  asm volatile("global_load_dwordx4 %0, %1, off sc0 sc1" : "=v"(d) : "v"(p) : "memory");
  return d;
}
__device__ __forceinline__ void st64_c(void* p, i32x2 v){
  asm volatile("global_store_dwordx2 %0, %1, off sc0 sc1" :: "v"(p), "v"(v) : "memory");
}
__device__ __forceinline__ unsigned ld32_c(const void* p){
  unsigned d;
  asm volatile("global_load_dword %0, %1, off sc0 sc1\n\ts_waitcnt vmcnt(0)"
               : "=v"(d) : "v"(p) : "memory");
  __builtin_amdgcn_sched_barrier(0);
  return d;
}
__device__ __forceinline__ void vmem_drain(){
  asm volatile("s_waitcnt vmcnt(0)" ::: "memory");
  __builtin_amdgcn_sched_barrier(0);   // rule-18 fence
}

// =====================================================================
// Kernel 1: pre0 = x @ Wih0^T + b_ih0 + b_hh0   (unchanged — validated)
// =====================================================================
__global__ __launch_bounds__(256)
void pre_gemm(const float* __restrict__ x,
              const float* __restrict__ Wih,
              const float* __restrict__ bih,
              const float* __restrict__ bhh,
              _Float16* __restrict__ pre0)
{
  __shared__ float As[128][36];
  const int tid  = threadIdx.x;
  const int lane = tid & 63;
  const int wave = tid >> 6;
  const int l15  = lane & 15;
  const int l4   = lane >> 4;
  const int n0   = blockIdx.x * 128;
  const int m0   = blockIdx.y * 128;
  const int qm   = wave >> 1;
  const int qn   = wave & 1;

  f32x4 acc[4][4];
  #pragma unroll
  for (int i = 0; i < 4; ++i)
    #pragma unroll
    for (int j = 0; j < 4; ++j) acc[i][j] = (f32x4){0.f,0.f,0.f,0.f};

  const int sr = tid >> 1;
  const int sh = tid & 1;
  const float* xrow = x + (size_t)(m0 + sr)*NH + sh*16;

  for (int kb = 0; kb < 32; ++kb){
    __syncthreads();
    {
      const float* src = xrow + kb*32;
      f32x4 v0 = *(const f32x4*)(src + 0);
      f32x4 v1 = *(const f32x4*)(src + 4);
      f32x4 v2 = *(const f32x4*)(src + 8);
      f32x4 v3 = *(const f32x4*)(src + 12);
      float* dst = &As[sr][sh*16];
      *(f32x4*)(dst + 0)  = v0;
      *(f32x4*)(dst + 4)  = v1;
      *(f32x4*)(dst + 8)  = v2;
      *(f32x4*)(dst + 12) = v3;
    }
    __syncthreads();

    bf16x8 ahi[4], alo[4];
    #pragma unroll
    for (int mt = 0; mt < 4; ++mt){
      const float* ap = &As[64*qm + 16*mt + l15][l4*8];
      #pragma unroll
      for (int j = 0; j < 8; ++j){
        float a = ap[j];
        unsigned short hb = bf16rne(a);
        ahi[mt][j] = (short)hb;
        alo[mt][j] = (short)bf16rne(a - bf16tof(hb));
      }
    }
    #pragma unroll
    for (int nf = 0; nf < 4; ++nf){
      const int c = n0 + 64*qn + 16*nf + l15;
      const float* wp = Wih + (size_t)c*NH + kb*32 + l4*8;
      bf16x8 bf;
      #pragma unroll
      for (int j = 0; j < 8; ++j) bf[j] = (short)bf16rne(wp[j]);
      #pragma unroll
      for (int mt = 0; mt < 4; ++mt){
        acc[mt][nf] = __builtin_amdgcn_mfma_f32_16x16x32_bf16(ahi[mt], bf, acc[mt][nf], 0,0,0);
        acc[mt][nf] = __builtin_amdgcn_mfma_f32_16x16x32_bf16(alo[mt], bf, acc[mt][nf], 0,0,0);
      }
    }
  }

  #pragma unroll
  for (int nf = 0; nf < 4; ++nf){
    const int c = n0 + 64*qn + 16*nf + l15;
    const float bv = bih[c] + bhh[c];
    #pragma unroll
    for (int mt = 0; mt < 4; ++mt){
      const int mb = m0 + 64*qm + 16*mt + l4*4;
      #pragma unroll
      for (int j = 0; j < 4; ++j)
        pre0[(size_t)(mb + j)*NH + c] = (_Float16)(acc[mt][nf][j] + bv);
    }
  }
}

// =====================================================================
// Kernel 2: 32-WG persistent recurrence. Per-WAVE completion counters
// (one 128B line per WG, atomicAdd), single __syncthreads per phase,
// tight poll, inline sc0sc1 dwordx4 gathers (R3-proven primitives).
// =====================================================================
__global__ __launch_bounds__(256, 1)
void rnn_seq(const float* __restrict__ h0in,
             const float* __restrict__ Wih,
             const float* __restrict__ Whh,
             const float* __restrict__ bih,
             const float* __restrict__ bhh,
             const _Float16* __restrict__ pre0,
             float* __restrict__ dout,
             char* __restrict__ ws)
{
  const int tid  = threadIdx.x;
  const int lane = tid & 63;
  const int wave = tid >> 6;
  const int l15  = lane & 15;
  const int l4   = lane >> 4;
  const int rank = blockIdx.x;     // 0..31
  const int c0   = rank * 32;

  // flags: 32 counters, each on its OWN 128-B line (atomicAdd parallelism)
  unsigned* flags = (unsigned*)ws;           // flag r at word r*32; memset/launch
  char* H0 = ws + 8192;                      // [2][32][1024] bf16
  char* H1 = ws + 8192 + 131072;

  // ---- static weight A-fragments: [0]=Whh0 [1]=Wih1 [2]=Whh1 (proven) ----
  bf16x8 wA[3][2][8];
  #pragma unroll
  for (int cf = 0; cf < 2; ++cf){
    const size_t row = (size_t)(c0 + cf*16 + l15) * NH;
    const float* s0 = Whh + row;
    const float* s1 = Wih + HH + row;
    const float* s2 = Whh + HH + row;
    #pragma unroll
    for (int s = 0; s < 8; ++s){
      const int k = wave*256 + s*32 + l4*8;
      #pragma unroll
      for (int j = 0; j < 8; ++j){
        wA[0][cf][s][j] = (short)bf16rne(s0[k+j]);
        wA[1][cf][s][j] = (short)bf16rne(s1[k+j]);
        wA[2][cf][s][j] = (short)bf16rne(s2[k+j]);
      }
    }
  }

  // ---- epilogue mapping: thread -> (batch, 4-col block), both layers ----
  const int eb   = tid >> 3;
  const int ecb  = tid & 7;
  const int ecol = c0 + ecb*4;

  f32x4 bias1;
  #pragma unroll
  for (int j = 0; j < 4; ++j)
    bias1[j] = bih[NH + ecol + j] + bhh[NH + ecol + j];

  // ---- initial state h(-1) -> parity-1 slots; per-wave flag ----
  {
    const float* hs0 = h0in + (size_t)eb*NH + ecol;
    const float* hs1 = h0in + (size_t)NB*NH + (size_t)eb*NH + ecol;
    i32x2 p0, p1;
    p0[0] = (int)bf16rne(hs0[0]) | ((int)bf16rne(hs0[1]) << 16);
    p0[1] = (int)bf16rne(hs0[2]) | ((int)bf16rne(hs0[3]) << 16);
    p1[0] = (int)bf16rne(hs1[0]) | ((int)bf16rne(hs1[1]) << 16);
    p1[1] = (int)bf16rne(hs1[2]) | ((int)bf16rne(hs1[3]) << 16);
    st64_c(H0 + 65536 + eb*2048 + ecol*2, p0);
    st64_c(H1 + 65536 + eb*2048 + ecol*2, p1);
  }
  vmem_drain();
  if (lane == 0) atomicAdd(&flags[rank*32], 1u);   // each wave: +1 (init -> 4)

  __shared__ float scr[4][8][16][20];   // padded (proven)
  long spins = 0;

  for (int p = 0; p <= T_SEQ; ++p){
    const bool doL0 = (p < T_SEQ);
    const bool doL1 = (p >= 1);

    // prefetch pre0 slice (plain cached load; consumed in epilogue)
    s16x4 praw = {0,0,0,0};
    if (doL0)
      praw = *(const s16x4*)(pre0 + (size_t)p*(NB*NH) + (size_t)eb*NH + ecol);

    // ---- per-wave poll: all 32 WG counters >= 4*(p+1) ----
    {
      const unsigned target = 4u * (unsigned)(p + 1);
      const unsigned* fp = flags + (lane & 31)*32;   // lane i -> flag i's line
      for (;;){
        unsigned f = ld32_c(fp);
        int ok = (lane >= 32) || (f >= target);
        if (__all(ok)) break;
        if (++spins > (1L << 21)) break;             // degrade, never hang
        if (spins > 4096) __builtin_amdgcn_s_sleep(1);
      }
    }

    // ---- gather state B-fragments (inline dwordx4, single drain) ----
    const char* h0rd = H0 + ((p-1)&1)*65536;
    const char* h1rd = H1 + ((p-2)&1)*65536;
    i32x4 g0[2][8], g1[2][8];
    #pragma unroll
    for (int bt = 0; bt < 2; ++bt){
      const int b = bt*16 + l15;
      #pragma unroll
      for (int s = 0; s < 8; ++s){
        const int d = wave*256 + s*32 + l4*8;
        g0[bt][s] = ld128_c(h0rd + b*2048 + d*2);
      }
    }
    if (doL1){
      #pragma unroll
      for (int bt = 0; bt < 2; ++bt){
        const int b = bt*16 + l15;
        #pragma unroll
        for (int s = 0; s < 8; ++s){
          const int d = wave*256 + s*32 + l4*8;
          g1[bt][s] = ld128_c(h1rd + b*2048 + d*2);
        }
      }
    }
    vmem_drain();

    // ---- MFMA partial sums over this wave's K-slice (proven mapping) ----
    f32x4 acc0[2][2] = {{{0,0,0,0},{0,0,0,0}},{{0,0,0,0},{0,0,0,0}}};
    f32x4 acc1[2][2] = {{{0,0,0,0},{0,0,0,0}},{{0,0,0,0},{0,0,0,0}}};
    #pragma unroll
    for (int cf = 0; cf < 2; ++cf){
      #pragma unroll
      for (int bt = 0; bt < 2; ++bt){
        #pragma unroll
        for (int s = 0; s < 8; ++s){
          bf16x8 b0 = __builtin_bit_cast(bf16x8, g0[bt][s]);
          if (doL0)
            acc0[cf][bt] = __builtin_amdgcn_mfma_f32_16x16x32_bf16(wA[0][cf][s], b0, acc0[cf][bt], 0,0,0);
          if (doL1){
            acc1[cf][bt] = __builtin_amdgcn_mfma_f32_16x16x32_bf16(wA[1][cf][s], b0, acc1[cf][bt], 0,0,0);
            bf16x8 b1 = __builtin_bit_cast(bf16x8, g1[bt][s]);
            acc1[cf][bt] = __builtin_amdgcn_mfma_f32_16x16x32_bf16(wA[2][cf][s], b1, acc1[cf][bt], 0,0,0);
          }
        }
      }
    }

    // ---- cross-wave K reduction via LDS (single barrier per phase) ----
    // WAR-safe without a pre-barrier: passing the poll for phase p proves
    // every wave of THIS WG flagged phase p-1, which is ordered after its
    // phase-(p-1) reduce reads and state stores.
    #pragma unroll
    for (int cf = 0; cf < 2; ++cf){
      #pragma unroll
      for (int bt = 0; bt < 2; ++bt){
        *(f32x4*)&scr[wave][(cf<<1)|bt][l15][l4*4]   = acc0[cf][bt];
        *(f32x4*)&scr[wave][4|(cf<<1)|bt][l15][l4*4] = acc1[cf][bt];
      }
    }
    __syncthreads();

    const int fL0 = ((ecb >> 2) << 1) | (eb >> 4);
    f32x4 s0v = {0,0,0,0}, s1v = {0,0,0,0};
    #pragma unroll
    for (int w = 0; w < 4; ++w){
      s0v += *(const f32x4*)&scr[w][fL0][eb & 15][(ecb & 3)*4];
      s1v += *(const f32x4*)&scr[w][4|fL0][eb & 15][(ecb & 3)*4];
    }

    // ---- activations; state stores; per-wave drain+flag; then dout ----
    float hv0[4], hv1[4];
    if (doL0){
      union { s16x4 v; _Float16 h[4]; } pu; pu.v = praw;
      #pragma unroll
      for (int j = 0; j < 4; ++j)
        hv0[j] = fast_tanh(s0v[j] + (float)pu.h[j]);
      i32x2 pk;
      pk[0] = (int)bf16rne(hv0[0]) | ((int)bf16rne(hv0[1]) << 16);
      pk[1] = (int)bf16rne(hv0[2]) | ((int)bf16rne(hv0[3]) << 16);
      st64_c(H0 + (p&1)*65536 + eb*2048 + ecol*2, pk);
    }
    if (doL1){
      #pragma unroll
      for (int j = 0; j < 4; ++j)
        hv1[j] = fast_tanh(s1v[j] + bias1[j]);
      i32x2 pk;
      pk[0] = (int)bf16rne(hv1[0]) | ((int)bf16rne(hv1[1]) << 16);
      pk[1] = (int)bf16rne(hv1[2]) | ((int)bf16rne(hv1[3]) << 16);
      st64_c(H1 + ((p-1)&1)*65536 + eb*2048 + ecol*2, pk);
    }

    vmem_drain();                                    // this wave's stores in fabric
    if (lane == 0) atomicAdd(&flags[rank*32], 1u);   // wave done with phase p

    // ---- HBM outputs off the critical chain ----
    if (doL1){
      f32x4 o = {hv1[0], hv1[1], hv1[2], hv1[3]};
      *(f32x4*)(dout + (size_t)(p-1)*(NB*NH) + (size_t)eb*NH + ecol) = o;
      if (p == T_SEQ)
        *(f32x4*)(dout + HIST_ELEMS + (size_t)NB*NH + (size_t)eb*NH + ecol) = o;
    }
    if (doL0 && p == T_SEQ-1){
      f32x4 o = {hv0[0], hv0[1], hv0[2], hv0[3]};
      *(f32x4*)(dout + HIST_ELEMS + (size_t)eb*NH + ecol) = o;
    }
  }
}

extern "C" void kernel_launch(void* const* d_in, const int* in_sizes, int n_in,
                              void* d_out, int out_size, void* d_ws, size_t ws_size,
                              hipStream_t stream)
{
  (void)in_sizes; (void)n_in; (void)out_size;
  const float* x   = (const float*)d_in[0];
  const float* h0  = (const float*)d_in[1];
  const float* Wih = (const float*)d_in[2];
  const float* Whh = (const float*)d_in[3];
  const float* bih = (const float*)d_in[4];
  const float* bhh = (const float*)d_in[5];
  float* out = (float*)d_out;
  char*  ws  = (char*)d_ws;

  const size_t PRE0_OFF = (size_t)1 << 20;
  const size_t NEED = PRE0_OFF + (size_t)T_SEQ*NB*NH*sizeof(_Float16);
  if (ws_size < NEED) return;

  _Float16* pre0 = (_Float16*)(ws + PRE0_OFF);

  hipMemsetAsync(ws, 0, 4096, stream);   // zero the 32 padded flag lines
  pre_gemm<<<dim3(8, 512), 256, 0, stream>>>(x, Wih, bih, bhh, pre0);
  rnn_seq<<<dim3(TEAM), 256, 0, stream>>>(h0, Wih, Whh, bih, bhh, pre0, out, ws);
}